// Round 4
// baseline (2736.184 us; speedup 1.0000x reference)
//
#include <hip/hip_runtime.h>

// ODE-GRU recurrence, B=128, L=2048, I=D=64.
// R8: shrink the sync domain. Model fit across R5/R7b: step = F + issue with
// F(8 waves)=1400cy, F(16 waves)=1740cy — the fixed cost is barrier skew +
// LDS round trips and it GROWS with wave count, while re-partitioning work
// over more waves grows total issue (fixed per-lane reduce overhead).
// R8 therefore uses 2 waves (128 threads) per batch:
//   wave w owns elements q in [32w,32w+32); lane = (e=l&31, half=l>>5).
//   Each lane holds 4 weight rows x 32-input chunk per round (64 f4 = 256
//   VGPR, all constant-indexed). Per round: 8 broadcast ds_read_b128 of the
//   h/t1 chunk, 4 dot32 partials, 4 shfl_xor(32) combines -> BOTH halves own
//   all 4 sums -> gates computed redundantly in-lane: no n-exchange, zero
//   divergence. 2 barriers/step remain (all-to-all is irreducible) but now
//   span only 2 waves. LDS traffic/step halves (each h-float feeds 4 MACs).
//   gx weights re-read from global each tile (L2-hot, issued before the
//   staging barrier) to keep VGPR ~350.
// Carried: gh linearity (M2=Whh@dw2, c2=Whh@db2 in d_ws), packed-fp32 dots,
// gx tile precompute, LDS-buffered output flush, masked staging.

#define NB    128
#define SEQ   2048
#define DIM   64
#define TILE  32
#define XS    68     // sh_x row stride (floats)
#define GS    194    // sh_gx row stride (floats)

typedef float f32x2 __attribute__((ext_vector_type(2)));

__device__ __forceinline__ float fast_rcp(float x) { return __builtin_amdgcn_rcpf(x); }

__device__ __forceinline__ float sigmoid_f(float v) {
    return fast_rcp(1.0f + __expf(-v));
}
__device__ __forceinline__ float tanh_f(float v) {
    float e = __expf(2.0f * v);
    return fmaf(-2.0f, fast_rcp(e + 1.0f), 1.0f);
}

// 32-element dot in packed fp32: 16 v_pk_fma_f32 in two chains + pk_add + add.
__device__ __forceinline__ float dot32p(const float4* w, const float4* h) {
    f32x2 a; a.x = 0.f; a.y = 0.f;
    f32x2 b; b.x = 0.f; b.y = 0.f;
#pragma unroll
    for (int i = 0; i < 8; i++) {
        f32x2 wlo; wlo.x = w[i].x; wlo.y = w[i].y;
        f32x2 whi; whi.x = w[i].z; whi.y = w[i].w;
        f32x2 hlo; hlo.x = h[i].x; hlo.y = h[i].y;
        f32x2 hhi; hhi.x = h[i].z; hhi.y = h[i].w;
        a = __builtin_elementwise_fma(wlo, hlo, a);
        b = __builtin_elementwise_fma(whi, hhi, b);
    }
    f32x2 s = a + b;
    return s.x + s.y;
}

// ---- prep: M2 = Whh @ dw2 (192x64), c2 = Whh @ db2 (192) ----
__global__ void odegru_prep(const float* __restrict__ w_hh,
                            const float* __restrict__ dw2,
                            const float* __restrict__ db2,
                            float* __restrict__ m2,   // 192*64
                            float* __restrict__ c2)   // 192
{
    const int idx = blockIdx.x * 256 + threadIdx.x;
    if (idx < 192 * 64) {
        const int r = idx >> 6, k = idx & 63;
        float s = 0.f;
#pragma unroll
        for (int j = 0; j < 64; j++) s = fmaf(w_hh[r * 64 + j], dw2[j * 64 + k], s);
        m2[idx] = s;
    }
    if (idx < 192) {
        float s = 0.f;
#pragma unroll
        for (int j = 0; j < 64; j++) s = fmaf(w_hh[idx * 64 + j], db2[j], s);
        c2[idx] = s;
    }
}

__global__ __launch_bounds__(128, 1)
void odegru_fused(const float* __restrict__ x,        // (B,L,I)
                  const float* __restrict__ tds,      // (B,L)
                  const int*   __restrict__ seq_lens, // (B)
                  const float* __restrict__ h0,       // (D)
                  const float* __restrict__ w_ih,     // (3D,I)
                  const float* __restrict__ w_hh,     // (3D,D)
                  const float* __restrict__ b_ih,     // (3D)
                  const float* __restrict__ b_hh,     // (3D)
                  const float* __restrict__ dw1,      // (D,D)
                  const float* __restrict__ db1,      // (D)
                  const float* __restrict__ dw2,      // (D,D)
                  const float* __restrict__ db2,      // (D)
                  const float* __restrict__ m2,       // (3D,D) = Whh@dw2
                  const float* __restrict__ c2,       // (3D)   = Whh@db2
                  float* __restrict__ out)            // (B,L,D) ++ (B,D)
{
    const int b    = blockIdx.x;
    const int tid  = threadIdx.x;      // 0..127
    const int w    = tid >> 6;         // wave 0/1
    const int lane = tid & 63;
    const int e    = lane & 31;
    const int half = lane >> 5;        // input-chunk half
    const int q    = (w << 5) | e;     // owned element 0..63
    const int j0   = half << 5;        // input chunk base (floats)
    const int seqlen = seq_lens[b];

    __shared__ float sh_h  [DIM];
    __shared__ float sh_t1 [DIM];
    __shared__ float sh_dt [TILE];
    __shared__ float sh_x  [TILE][XS];
    __shared__ float sh_gx [TILE][GS];
    __shared__ float sh_out[TILE][DIM];

    // ---- persistent round weights: 8 rows x 8 float4 = 256 VGPR ----
    float4 wU[8], w0[8], w1[8], w2[8], v0[8], v1[8], v2[8], vH[8];
    const int r0 = q * 16 + half * 8;            // row q, chunk half (f4 units)
    const int r1 = (64 + q) * 16 + half * 8;     // row 64+q
    const int r2 = (128 + q) * 16 + half * 8;    // row 128+q
    {
        const float4* dw1v = (const float4*)dw1;
        const float4* dw2v = (const float4*)dw2;
        const float4* whhv = (const float4*)w_hh;
        const float4* m2v  = (const float4*)m2;
#pragma unroll
        for (int i = 0; i < 8; i++) {
            wU[i] = dw1v[r0 + i];    // u   = dw1_q @ h
            w0[i] = whhv[r0 + i];    // G0  = Whh_q @ h
            w1[i] = whhv[r1 + i];    // G1  = Whh_{64+q} @ h
            w2[i] = whhv[r2 + i];    // G2  = Whh_{128+q} @ h
            v0[i] = m2v [r0 + i];    // m0  = M2_q @ t1
            v1[i] = m2v [r1 + i];    // m1  = M2_{64+q} @ t1
            v2[i] = m2v [r2 + i];    // m2  = M2_{128+q} @ t1
            vH[i] = dw2v[r0 + i];    // hot = dw2_q @ t1
        }
    }
    const float db1q = db1[q];
    const float bh0  = b_hh[q],       bh1 = b_hh[64 + q], bh2 = b_hh[128 + q];
    const float c0v  = c2[q],         c1v = c2[64 + q],   c2n = c2[128 + q];
    const float db2q = db2[q];
    const float bx0  = b_ih[q],       bx1 = b_ih[64 + q], bx2 = b_ih[128 + q];

    if (tid < DIM) sh_h[tid] = h0[tid];   // visible after first staging barrier

    const float* xb  = x   + (size_t)b * SEQ * DIM;
    const float* tdb = tds + (size_t)b * SEQ;
    float* outb = out + (size_t)b * SEQ * DIM;
    float* finb = out + (size_t)NB * SEQ * DIM + (size_t)b * DIM;
    const float4* wihv = (const float4*)w_ih;

    for (int t0 = 0; t0 < SEQ; t0 += TILE) {
        // ---- gx weights for this tile (global, L2/L3-hot; in flight
        //      across the staging barrier) ----
        float4 wiA[8], wiB[8], wiC[8];
#pragma unroll
        for (int i = 0; i < 8; i++) {
            wiA[i] = wihv[r0 + i];
            wiB[i] = wihv[r1 + i];
            wiC[i] = wihv[r2 + i];
        }

        // ---- stage x tile (masked) + dt tile; 512 f4 / 128 thr = 4 each ----
        {
            const float4* src = (const float4*)(xb + (size_t)t0 * DIM);
#pragma unroll
            for (int k = 0; k < 4; k++) {
                const int idx = tid + 128 * k;          // 0..511
                const int ts0 = idx >> 4, j = idx & 15;
                float4 vx = src[idx];
                if (t0 + ts0 >= seqlen) vx = make_float4(0.f, 0.f, 0.f, 0.f);
                *(float4*)&sh_x[ts0][4 * j] = vx;
            }
            if (tid < TILE) {
                const int t = t0 + tid;
                sh_dt[tid] = (t < seqlen) ? tdb[t] : 0.0f;
            }
        }
        __syncthreads();

        // ---- gx tile: lane computes dot32 partials for rows {q,64+q,128+q},
        //      shfl_xor(32) combine; half0 writes ----
        for (int ts = 0; ts < TILE; ts++) {
            const float4* xv = (const float4*)&sh_x[ts][j0];
            float4 x4[8];
#pragma unroll
            for (int i = 0; i < 8; i++) x4[i] = xv[i];
            float A0 = dot32p(wiA, x4);
            float A1 = dot32p(wiB, x4);
            float A2 = dot32p(wiC, x4);
            A0 += __shfl_xor(A0, 32, 64);
            A1 += __shfl_xor(A1, 32, 64);
            A2 += __shfl_xor(A2, 32, 64);
            if (half == 0) {
                sh_gx[ts][q]        = A0 + bx0;
                sh_gx[ts][64 + q]   = A1 + bx1;
                sh_gx[ts][128 + q]  = A2 + bx2;
            }
        }
        __syncthreads();   // gx + sh_h visible to both waves

#pragma unroll 1
        for (int ts = 0; ts < TILE; ts++) {
            const int t = t0 + ts;

            // prefetch scalars (independent LDS reads)
            const float dtv = sh_dt[ts];
            const float g0v = sh_gx[ts][q];
            const float g1v = sh_gx[ts][64 + q];
            const float g2v = sh_gx[ts][128 + q];
            const float hq  = sh_h[q];

            // ---- Round 1 (read h chunk): 4 dot32 partials + combine ----
            const float4* hv = (const float4*)&sh_h[j0];
            float4 h4[8];
#pragma unroll
            for (int i = 0; i < 8; i++) h4[i] = hv[i];
            float sU = dot32p(wU, h4);
            float s0 = dot32p(w0, h4);
            float s1 = dot32p(w1, h4);
            float s2 = dot32p(w2, h4);
            sU += __shfl_xor(sU, 32, 64);
            s0 += __shfl_xor(s0, 32, 64);
            s1 += __shfl_xor(s1, 32, 64);
            s2 += __shfl_xor(s2, 32, 64);
            const float t1v = tanh_f(sU + db1q);
            if (half == 0) sh_t1[q] = t1v;
            __syncthreads();   // t1 visible (2 waves only)

            // ---- Round 2 (read t1 chunk): 4 dot32 partials + combine ----
            const float4* tv = (const float4*)&sh_t1[j0];
            float4 t4[8];
#pragma unroll
            for (int i = 0; i < 8; i++) t4[i] = tv[i];
            float m0 = dot32p(v0, t4);
            float m1 = dot32p(v1, t4);
            float m2s = dot32p(v2, t4);
            float sH = dot32p(vH, t4);
            m0  += __shfl_xor(m0, 32, 64);
            m1  += __shfl_xor(m1, 32, 64);
            m2s += __shfl_xor(m2s, 32, 64);
            sH  += __shfl_xor(sH, 32, 64);

            // ---- gates: computed redundantly on both halves (no exchange,
            //      no divergence) ----
            const float r   = sigmoid_f(g0v + s0 + fmaf(dtv, m0 + c0v, bh0));
            const float z   = sigmoid_f(g1v + s1 + fmaf(dtv, m1 + c1v, bh1));
            const float ghn = s2 + fmaf(dtv, m2s + c2n, bh2);
            const float n   = tanh_f(fmaf(r, ghn, g2v));
            const float ho  = fmaf(dtv, sH + db2q, hq);
            const float hn  = fmaf(z, ho - n, n);   // (1-z)*n + z*ho
            if (half == 0) {
                sh_h[q] = hn;
                sh_out[ts][q] = hn;
                if (t == seqlen - 1) finb[q] = hn;
            }
            __syncthreads();   // h visible (2 waves only)
        }

        // ---- flush output tile: 512 f4 / 128 thr = 4 each ----
        {
            float4* dst = (float4*)(outb + (size_t)t0 * DIM);
            const float4* srcv = (const float4*)(&sh_out[0][0]);
#pragma unroll
            for (int k = 0; k < 4; k++) dst[tid + 128 * k] = srcv[tid + 128 * k];
        }
    }
}

extern "C" void kernel_launch(void* const* d_in, const int* in_sizes, int n_in,
                              void* d_out, int out_size, void* d_ws, size_t ws_size,
                              hipStream_t stream) {
    const float* x    = (const float*)d_in[0];
    const float* tds  = (const float*)d_in[1];
    const int*   sl   = (const int*)  d_in[2];
    const float* h0   = (const float*)d_in[3];
    const float* w_ih = (const float*)d_in[4];
    const float* w_hh = (const float*)d_in[5];
    const float* b_ih = (const float*)d_in[6];
    const float* b_hh = (const float*)d_in[7];
    const float* dw1  = (const float*)d_in[8];
    const float* db1  = (const float*)d_in[9];
    const float* dw2  = (const float*)d_in[10];
    const float* db2  = (const float*)d_in[11];
    float* out = (float*)d_out;

    float* m2 = (float*)d_ws;              // 192*64 floats
    float* c2 = m2 + 192 * 64;             // 192 floats

    odegru_prep<<<dim3(48), dim3(256), 0, stream>>>(w_hh, dw2, db2, m2, c2);
    odegru_fused<<<dim3(NB), dim3(128), 0, stream>>>(
        x, tds, sl, h0, w_ih, w_hh, b_ih, b_hh, dw1, db1, dw2, db2, m2, c2, out);
}

// Round 5
// 2027.437 us; speedup vs baseline: 1.3496x; 1.3496x over previous
//
#include <hip/hip_runtime.h>

// ODE-GRU recurrence, B=128, L=2048, I=D=64.
// R9: 4 waves + LDS diet. Empirical step-time vs wave count {16w:2670,
// 8w:1935, 2w:3137 cy} killed the barrier-skew model; the fit is LDS-pipe
// occupancy: every wave redundantly re-reads full h/t1 each round
// (replication ~ wave count), ~960 cy/step at 8 waves. R8's 2-wave loss came
// from shfl_xor(32)=ds_permute (MORE LDS ops) + unhidden latency.
// R9: 256 threads (4 waves, 1/SIMD), quad-per-element (q=tid>>2, chunk
// p=tid&3, dot16 + DPP quad reduce — cross-lane stays in-VALU):
//   - all 8 recurrence rows + 3 gx rows persistent in VGPRs (176 regs)
//   - gates computed redundantly per quad: no n-exchange, no divergence
//   - gx packed float4 {g0,g1,g2,dt} at sh_gx[ts][4q]: 1 b128 prefetch/step
//   - no sh_x: gx phase reads x chunks from global (dedup'd, L2-hot, dbuf)
//   - no sh_out: p==0 stores h straight to global (64B/wave contiguous)
// LDS ops/step ~960 -> ~500 cy; 2 barriers/step now span 4 waves.
// Carried: gh linearity (M2=Whh@dw2, c2=Whh@db2 in d_ws), packed-fp32 dots,
// DPP quad butterflies, masked x/dt semantics (reference runs masked steps).

#define NB    128
#define SEQ   2048
#define DIM   64
#define TILE  32
#define GXS   260   // sh_gx row stride (floats); rows hold [4q+{0,1,2}] + dt in .w

typedef float f32x2 __attribute__((ext_vector_type(2)));

__device__ __forceinline__ float fast_rcp(float x) { return __builtin_amdgcn_rcpf(x); }

__device__ __forceinline__ float sigmoid_f(float v) {
    return fast_rcp(1.0f + __expf(-v));
}
__device__ __forceinline__ float tanh_f(float v) {
    float e = __expf(2.0f * v);
    return fmaf(-2.0f, fast_rcp(e + 1.0f), 1.0f);
}

template <int CTRL>
__device__ __forceinline__ float dpp_f(float v) {
    return __int_as_float(__builtin_amdgcn_mov_dpp(__float_as_int(v), CTRL, 0xF, 0xF, true));
}

// Butterfly sum over a lane-quad; every lane of the quad gets the total.
__device__ __forceinline__ float quad_reduce(float v) {
    v += dpp_f<0xB1>(v);
    v += dpp_f<0x4E>(v);
    return v;
}

// 16-element dot in packed fp32: 8 v_pk_fma_f32 + pk_add + add.
__device__ __forceinline__ float dot16p(const float4* w, const float4* h) {
    f32x2 a; a.x = 0.f; a.y = 0.f;
    f32x2 b; b.x = 0.f; b.y = 0.f;
#pragma unroll
    for (int i = 0; i < 4; i++) {
        f32x2 wlo; wlo.x = w[i].x; wlo.y = w[i].y;
        f32x2 whi; whi.x = w[i].z; whi.y = w[i].w;
        f32x2 hlo; hlo.x = h[i].x; hlo.y = h[i].y;
        f32x2 hhi; hhi.x = h[i].z; hhi.y = h[i].w;
        a = __builtin_elementwise_fma(wlo, hlo, a);
        b = __builtin_elementwise_fma(whi, hhi, b);
    }
    f32x2 s = a + b;
    return s.x + s.y;
}

// ---- prep: M2 = Whh @ dw2 (192x64), c2 = Whh @ db2 (192) ----
__global__ void odegru_prep(const float* __restrict__ w_hh,
                            const float* __restrict__ dw2,
                            const float* __restrict__ db2,
                            float* __restrict__ m2,   // 192*64
                            float* __restrict__ c2)   // 192
{
    const int idx = blockIdx.x * 256 + threadIdx.x;
    if (idx < 192 * 64) {
        const int r = idx >> 6, k = idx & 63;
        float s = 0.f;
#pragma unroll
        for (int j = 0; j < 64; j++) s = fmaf(w_hh[r * 64 + j], dw2[j * 64 + k], s);
        m2[idx] = s;
    }
    if (idx < 192) {
        float s = 0.f;
#pragma unroll
        for (int j = 0; j < 64; j++) s = fmaf(w_hh[idx * 64 + j], db2[j], s);
        c2[idx] = s;
    }
}

__global__ __launch_bounds__(256, 1)
void odegru_fused(const float* __restrict__ x,        // (B,L,I)
                  const float* __restrict__ tds,      // (B,L)
                  const int*   __restrict__ seq_lens, // (B)
                  const float* __restrict__ h0,       // (D)
                  const float* __restrict__ w_ih,     // (3D,I)
                  const float* __restrict__ w_hh,     // (3D,D)
                  const float* __restrict__ b_ih,     // (3D)
                  const float* __restrict__ b_hh,     // (3D)
                  const float* __restrict__ dw1,      // (D,D)
                  const float* __restrict__ db1,      // (D)
                  const float* __restrict__ dw2,      // (D,D)
                  const float* __restrict__ db2,      // (D)
                  const float* __restrict__ m2,       // (3D,D) = Whh@dw2
                  const float* __restrict__ c2,       // (3D)   = Whh@db2
                  float* __restrict__ out)            // (B,L,D) ++ (B,D)
{
    const int b   = blockIdx.x;
    const int tid = threadIdx.x;      // 0..255
    const int q   = tid >> 2;         // owned element 0..63
    const int p   = tid & 3;          // K-chunk: [16p, 16p+16)
    const int seqlen = seq_lens[b];

    __shared__ float sh_h [DIM];
    __shared__ float sh_t1[DIM];
    __shared__ float sh_gx[TILE][GXS];

    // ---- persistent weights: 11 rows x 4 float4 = 176 VGPR ----
    float4 wU[4], w0[4], w1[4], w2[4], v0[4], v1[4], v2[4], vH[4];
    float4 wi0[4], wi1[4], wi2[4];
    const int r0 = q * 16 + p * 4;            // row q, chunk p (f4 units)
    const int r1 = (64 + q) * 16 + p * 4;     // row 64+q
    const int r2 = (128 + q) * 16 + p * 4;    // row 128+q
    {
        const float4* dw1v = (const float4*)dw1;
        const float4* dw2v = (const float4*)dw2;
        const float4* whhv = (const float4*)w_hh;
        const float4* m2v  = (const float4*)m2;
        const float4* wihv = (const float4*)w_ih;
#pragma unroll
        for (int i = 0; i < 4; i++) {
            wU[i]  = dw1v[r0 + i];    // u   = dw1_q @ h
            w0[i]  = whhv[r0 + i];    // G0  = Whh_q @ h
            w1[i]  = whhv[r1 + i];    // G1  = Whh_{64+q} @ h
            w2[i]  = whhv[r2 + i];    // G2  = Whh_{128+q} @ h
            v0[i]  = m2v [r0 + i];    // m0  = M2_q @ t1
            v1[i]  = m2v [r1 + i];    // m1  = M2_{64+q} @ t1
            v2[i]  = m2v [r2 + i];    // m2  = M2_{128+q} @ t1
            vH[i]  = dw2v[r0 + i];    // hot = dw2_q @ t1
            wi0[i] = wihv[r0 + i];    // gx rows
            wi1[i] = wihv[r1 + i];
            wi2[i] = wihv[r2 + i];
        }
    }
    const float db1q = db1[q];
    const float bh0 = b_hh[q], bh1 = b_hh[64 + q], bh2 = b_hh[128 + q];
    const float c0v = c2[q],   c1v = c2[64 + q],   c2n = c2[128 + q];
    const float db2q = db2[q];
    const float bx0 = b_ih[q], bx1 = b_ih[64 + q], bx2 = b_ih[128 + q];

    if (tid < DIM) sh_h[tid] = h0[tid];   // visible after first gx barrier

    const float* xb  = x   + (size_t)b * SEQ * DIM;
    const float* tdb = tds + (size_t)b * SEQ;
    float* outb = out + (size_t)b * SEQ * DIM;
    float* finb = out + (size_t)NB * SEQ * DIM + (size_t)b * DIM;
    const float4* xsrc = (const float4*)xb;

    for (int t0 = 0; t0 < SEQ; t0 += TILE) {
        // ---- gx phase: per ts read x chunk from global (dedup'd in-wave,
        //      L2-hot, double-buffered), 3 dot16 + quad reduce, pack-write
        //      {g0,g1,g2,dt} to sh_gx[ts][4q]. No inner barriers — waves
        //      drift freely; one barrier at the end. ----
        {
            float4 xa[4];
#pragma unroll
            for (int i = 0; i < 4; i++) xa[i] = xsrc[(size_t)t0 * 16 + 4 * p + i];
            for (int ts = 0; ts < TILE; ts++) {
                const int t = t0 + ts;
                const bool live = (t < seqlen);
                const float dtv = live ? tdb[t] : 0.0f;
                float4 xn[4] = { xa[0], xa[1], xa[2], xa[3] };
                if (ts + 1 < TILE) {
#pragma unroll
                    for (int i = 0; i < 4; i++)
                        xn[i] = xsrc[(size_t)(t + 1) * 16 + 4 * p + i];
                }
                const float A0 = quad_reduce(dot16p(wi0, xa));
                const float A1 = quad_reduce(dot16p(wi1, xa));
                const float A2 = quad_reduce(dot16p(wi2, xa));
                if (p == 0) {
                    float4 gxw;
                    gxw.x = live ? A0 + bx0 : bx0;   // masked x -> gx = b_ih
                    gxw.y = live ? A1 + bx1 : bx1;
                    gxw.z = live ? A2 + bx2 : bx2;
                    gxw.w = dtv;                     // masked dt -> 0
                    *(float4*)&sh_gx[ts][4 * q] = gxw;
                }
#pragma unroll
                for (int i = 0; i < 4; i++) xa[i] = xn[i];
            }
        }
        __syncthreads();   // gx tile + sh_h visible

#pragma unroll 1
        for (int ts = 0; ts < TILE; ts++) {
            const int t = t0 + ts;

            // ---- prefetch: 1 b128 (g0,g1,g2,dt) + 1 b32 (hq) ----
            const float4 gx4 = *(const float4*)&sh_gx[ts][4 * q];
            const float  hq  = sh_h[q];

            // ---- Round 1 (read h chunk): 4 dot16 + quad reduces ----
            const float4* hv = (const float4*)sh_h;
            float4 h4[4] = { hv[4 * p], hv[4 * p + 1], hv[4 * p + 2], hv[4 * p + 3] };
            const float sU = quad_reduce(dot16p(wU, h4));
            const float s0 = quad_reduce(dot16p(w0, h4));
            const float s1 = quad_reduce(dot16p(w1, h4));
            const float s2 = quad_reduce(dot16p(w2, h4));
            const float t1v = tanh_f(sU + db1q);
            if (p == 0) sh_t1[q] = t1v;
            __syncthreads();   // t1 visible (4 waves)

            // ---- Round 2 (read t1 chunk): 4 dot16 + quad reduces ----
            const float4* tv = (const float4*)sh_t1;
            float4 t4[4] = { tv[4 * p], tv[4 * p + 1], tv[4 * p + 2], tv[4 * p + 3] };
            const float m0  = quad_reduce(dot16p(v0, t4));
            const float m1  = quad_reduce(dot16p(v1, t4));
            const float m2s = quad_reduce(dot16p(v2, t4));
            const float sH  = quad_reduce(dot16p(vH, t4));

            // ---- gates: redundant per quad (no exchange, no divergence) ----
            const float dtv = gx4.w;
            const float r   = sigmoid_f(gx4.x + s0 + fmaf(dtv, m0 + c0v, bh0));
            const float z   = sigmoid_f(gx4.y + s1 + fmaf(dtv, m1 + c1v, bh1));
            const float ghn = s2 + fmaf(dtv, m2s + c2n, bh2);
            const float n   = tanh_f(fmaf(r, ghn, gx4.z));
            const float ho  = fmaf(dtv, sH + db2q, hq);
            const float hn  = fmaf(z, ho - n, n);   // (1-z)*n + z*ho
            if (p == 0) {
                sh_h[q] = hn;
                outb[(size_t)t * DIM + q] = hn;      // 64B contiguous per wave
                if (t == seqlen - 1) finb[q] = hn;
            }
            __syncthreads();   // h visible (4 waves)
        }
    }
}

extern "C" void kernel_launch(void* const* d_in, const int* in_sizes, int n_in,
                              void* d_out, int out_size, void* d_ws, size_t ws_size,
                              hipStream_t stream) {
    const float* x    = (const float*)d_in[0];
    const float* tds  = (const float*)d_in[1];
    const int*   sl   = (const int*)  d_in[2];
    const float* h0   = (const float*)d_in[3];
    const float* w_ih = (const float*)d_in[4];
    const float* w_hh = (const float*)d_in[5];
    const float* b_ih = (const float*)d_in[6];
    const float* b_hh = (const float*)d_in[7];
    const float* dw1  = (const float*)d_in[8];
    const float* db1  = (const float*)d_in[9];
    const float* dw2  = (const float*)d_in[10];
    const float* db2  = (const float*)d_in[11];
    float* out = (float*)d_out;

    float* m2 = (float*)d_ws;              // 192*64 floats
    float* c2 = m2 + 192 * 64;             // 192 floats

    odegru_prep<<<dim3(48), dim3(256), 0, stream>>>(w_hh, dw2, db2, m2, c2);
    odegru_fused<<<dim3(NB), dim3(256), 0, stream>>>(
        x, tds, sl, h0, w_ih, w_hh, b_ih, b_hh, dw1, db1, dw2, db2, m2, c2, out);
}